// Round 3
// baseline (223.345 us; speedup 1.0000x reference)
//
#include <hip/hip_runtime.h>
#include <hip/hip_bf16.h>

#pragma clang fp contract(off)

#define B_N 32
#define A_N 32526
#define C_N 20
#define K_N 1000
#define NE 32   // ceil(A_N / 1024)

typedef unsigned long long u64;

// ---------------------------------------------------------------- kernel 1
// pscore[b,a] = sigmoid(max_c logits)  (sigmoid monotone => max commutes)
__global__ void k1_score(const float* __restrict__ pcls,
                         float* __restrict__ pscore, int total)
{
    int t = blockIdx.x * blockDim.x + threadIdx.x;
    if (t >= total) return;
    const float4* p = (const float4*)(pcls + (size_t)t * C_N);
    float m = -INFINITY;
#pragma unroll
    for (int q = 0; q < 5; ++q) {
        float4 v = p[q];
        m = fmaxf(m, fmaxf(fmaxf(v.x, v.y), fmaxf(v.z, v.w)));
    }
    double e = exp(-(double)m);
    pscore[t] = (float)(1.0 / (1.0 + e));
}

// ---------------------------------------------------------------- kernel 2
// per-batch exact top-K, JAX tie semantics (desc value, asc index).
// 2-bit-per-round MSB descent with packed counts (1 barrier/round),
// index descent for ties (fast path when need==1), ballot compaction,
// then O(K^2/P) rank computation via LDS broadcast (no sort).
__global__ void __launch_bounds__(1024)
k2_topk(const float* __restrict__ pscore,
        int* __restrict__ topi, float* __restrict__ topv)
{
    const int b = blockIdx.x;
    const int tid = threadIdx.x;
    const int lane = tid & 63;
    const int wv = tid >> 6;
    const float* ps = pscore + (size_t)b * A_N;

    __shared__ u64 wsum[2][16];
    __shared__ u64 skey[1024];
    __shared__ unsigned cnt_s;

    if (tid == 0) cnt_s = 0;

    // cache my keys (score bits; scores in (0,1] so sign bit clear)
    unsigned key[NE];
#pragma unroll
    for (int i = 0; i < NE; ++i) {
        int a = tid + i * 1024;
        key[i] = (a < A_N) ? __float_as_uint(ps[a]) : 0u;
    }

    int slot = 0;
    // block-wide u64 sum, one barrier per call (double-buffered wsum)
    auto blockSum = [&](u64 c) -> u64 {
#pragma unroll
        for (int off = 32; off > 0; off >>= 1) c += __shfl_down(c, off);
        if (lane == 0) wsum[slot][wv] = c;
        __syncthreads();
        u64 t2 = 0;
#pragma unroll
        for (int w = 0; w < 16; ++w) t2 += wsum[slot][w];
        slot ^= 1;
        return t2;
    };
    auto blockMin = [&](u64 c) -> u64 {
#pragma unroll
        for (int off = 32; off > 0; off >>= 1) {
            u64 o = __shfl_down(c, off);
            c = o < c ? o : c;
        }
        if (lane == 0) wsum[slot][wv] = c;
        __syncthreads();
        u64 t2 = ~0ull;
#pragma unroll
        for (int w = 0; w < 16; ++w) { u64 o = wsum[slot][w]; t2 = o < t2 ? o : t2; }
        slot ^= 1;
        return t2;
    };

    // value descent: V = exact K-th largest 32-bit score-bit value
    unsigned V = 0;
    for (int sh = 29; sh >= 1; sh -= 2) {
        unsigned X1 = V | (1u << sh), X2 = V | (2u << sh), X3 = V | (3u << sh);
        unsigned c1 = 0, c2 = 0, c3 = 0;
#pragma unroll
        for (int i = 0; i < NE; ++i) {
            unsigned k = key[i];
            c1 += (k >= X1); c2 += (k >= X2); c3 += (k >= X3);
        }
        u64 s = blockSum((u64)c1 | ((u64)c2 << 21) | ((u64)c3 << 42));
        unsigned s1 = (unsigned)(s & 0x1FFFFFu);
        unsigned s2 = (unsigned)((s >> 21) & 0x1FFFFFu);
        unsigned s3 = (unsigned)(s >> 42);
        if (s3 >= K_N) V = X3; else if (s2 >= K_N) V = X2; else if (s1 >= K_N) V = X1;
    }
    {   // bit 0
        unsigned X = V | 1u, c = 0;
#pragma unroll
        for (int i = 0; i < NE; ++i) c += (key[i] >= X);
        if (blockSum(c) >= K_N) V = X;
    }

    // nAbove = count(key > V); need = ties to take
    unsigned c0 = 0;
#pragma unroll
    for (int i = 0; i < NE; ++i) c0 += (key[i] > V);
    unsigned nAbove = (unsigned)blockSum(c0);
    unsigned need = K_N - nAbove;

    // idxThr = need-th smallest index among ties (keys == V)
    unsigned idxThr;
    if (need == 1) {
        unsigned mn = 0xFFFFFFFFu;
#pragma unroll
        for (int i = 0; i < NE; ++i) {
            int a = tid + i * 1024;
            if (a < A_N && key[i] == V && (unsigned)a < mn) mn = (unsigned)a;
        }
        idxThr = (unsigned)blockMin(mn);
    } else {
        unsigned T = 0;
        for (int sh = 13; sh >= 1; sh -= 2) {
            unsigned X1 = T | (1u << sh), X2 = T | (2u << sh), X3 = T | (3u << sh);
            unsigned c1 = 0, c2 = 0, c3 = 0;
#pragma unroll
            for (int i = 0; i < NE; ++i) {
                int a = tid + i * 1024;
                bool tie = (a < A_N) && (key[i] == V);
                c1 += (tie && (unsigned)a < X1);
                c2 += (tie && (unsigned)a < X2);
                c3 += (tie && (unsigned)a < X3);
            }
            u64 s = blockSum((u64)c1 | ((u64)c2 << 21) | ((u64)c3 << 42));
            unsigned s1 = (unsigned)(s & 0x1FFFFFu);
            unsigned s2 = (unsigned)((s >> 21) & 0x1FFFFFu);
            unsigned s3 = (unsigned)(s >> 42);
            if (s3 < need) T = X3; else if (s2 < need) T = X2; else if (s1 < need) T = X1;
        }
        {   // bit 0
            unsigned X = T | 1u, c = 0;
#pragma unroll
            for (int i = 0; i < NE; ++i) {
                int a = tid + i * 1024;
                c += ((a < A_N) && key[i] == V && (unsigned)a < X);
            }
            if (blockSum(c) < need) T = X;
        }
        idxThr = T;
    }

    // ballot compaction of exactly K_N winners (arbitrary order)
#pragma unroll
    for (int i = 0; i < NE; ++i) {
        int a = tid + i * 1024;
        bool win = (a < A_N) &&
                   (key[i] > V || (key[i] == V && (unsigned)a <= idxThr));
        u64 wm = __ballot(win);
        unsigned base = 0;
        if (lane == 0 && wm) base = atomicAdd(&cnt_s, (unsigned)__popcll(wm));
        base = __shfl(base, 0);
        if (win) {
            unsigned pos = base + (unsigned)__popcll(wm & ((1ull << lane) - 1ull));
            if (pos < 1024)
                skey[pos] = ((u64)key[i] << 32) |
                            (u64)(0xFFFFFFFFu - (unsigned)a);
        }
    }
    __syncthreads();

    // rank = #{winner keys > mine} (keys unique) -> exact sorted position
    if (tid < K_N) {
        u64 myk = skey[tid];
        unsigned rank = 0;
        for (int j = 0; j < K_N; ++j) rank += (skey[j] > myk);
        topi[(size_t)b * K_N + rank] = (int)(0xFFFFFFFFu - (unsigned)(myk & 0xFFFFFFFFull));
        topv[(size_t)b * K_N + rank] = __uint_as_float((unsigned)(myk >> 32));
    }
}

// ---------------------------------------------------------------- kernel 3
__global__ void k3_decode(const float* __restrict__ ptxywh,
                          const float* __restrict__ pcls,
                          const float* __restrict__ anchors,
                          const int* __restrict__ topi,
                          float4* __restrict__ boxesws,
                          int* __restrict__ labelsws,
                          float* __restrict__ out)
{
    int t = blockIdx.x * blockDim.x + threadIdx.x;
    if (t >= B_N * K_N) return;
    int b = t / K_N;
    int a = topi[t];

    float4 tb = ((const float4*)ptxywh)[(size_t)b * A_N + a];
    float4 an = ((const float4*)anchors)[a];

    float xx = an.x + (tb.x * 0.1f) * an.z;
    float yy = an.y + (tb.y * 0.1f) * an.w;
    float ww = an.z * (float)exp((double)(tb.z * 0.2f));
    float hh = an.w * (float)exp((double)(tb.w * 0.2f));
    float hw = ww * 0.5f, hh2 = hh * 0.5f;
    boxesws[t] = make_float4(xx - hw, yy - hh2, xx + hw, yy + hh2);

    const float4* pc = (const float4*)(pcls + ((size_t)b * A_N + a) * C_N);
    float m = -INFINITY; int lab = 0;
#pragma unroll
    for (int q = 0; q < 5; ++q) {
        float4 v = pc[q];
        if (v.x > m) { m = v.x; lab = q * 4 + 0; }
        if (v.y > m) { m = v.y; lab = q * 4 + 1; }
        if (v.z > m) { m = v.z; lab = q * 4 + 2; }
        if (v.w > m) { m = v.w; lab = q * 4 + 3; }
    }
    labelsws[t] = lab + 1;

    out[t] = (float)b;                                 // ids_batch
    out[5 * B_N * K_N + t] = (float)(lab + 1);         // labels
}

// ---------------------------------------------------------------- kernel 4
// suppression bitmask, TRANSPOSED layout: maskT[(b*16 + w)*1024 + i]
// bit j of word w of row i <=> iou(i, w*64+j) > 0.5, j != i
__global__ void k4_mask(const float4* __restrict__ boxesws,
                        const int* __restrict__ labelsws,
                        u64* __restrict__ maskT)
{
    const int b = blockIdx.y;
    const int tid = threadIdx.x;
    __shared__ float4 obox[K_N];
    __shared__ float oarea[K_N];

    for (int idx = tid; idx < K_N; idx += 256) {
        float4 bx = boxesws[(size_t)b * K_N + idx];
        float off = (float)labelsws[(size_t)b * K_N + idx] * 10.0f;
        float l = bx.x + off, t2 = bx.y + off, r = bx.z + off, bo = bx.w + off;
        obox[idx] = make_float4(l, t2, r, bo);
        oarea[idx] = (r - l) * (bo - t2);
    }
    __syncthreads();

    const int il = tid & 63;
    const int i = blockIdx.x * 64 + il;
    if (i >= K_N) return;
    float4 bi = obox[i];
    float ai = oarea[i];
#pragma unroll
    for (int p = 0; p < 4; ++p) {
        int w = (tid >> 6) + p * 4;
        u64 word = 0ull;
        for (int jj = 0; jj < 64; ++jj) {
            int j = w * 64 + jj;
            if (j < K_N && j != i) {
                float4 bj = obox[j];
                float lx = fmaxf(bi.x, bj.x);
                float ly = fmaxf(bi.y, bj.y);
                float rx = fminf(bi.z, bj.z);
                float ry = fminf(bi.w, bj.w);
                float wx = fmaxf(rx - lx, 0.0f);
                float wy = fmaxf(ry - ly, 0.0f);
                float inter = wx * wy;
                float uni = ai + oarea[j] - inter;
                float den = fmaxf(uni, 1e-9f);
                float iou = inter / den;
                if (iou > 0.5f) word |= (1ull << jj);
            }
        }
        maskT[((size_t)b * 16 + w) * 1024 + i] = word;
    }
}

// ---------------------------------------------------------------- kernel 5
// greedy NMS scan, one 1024-thread block per batch, transposed mask.
// Thread t = candidate row t; wave d runs chunk d's 64-step serial greedy;
// symmetric IoU makes cross-chunk suppression a single AND per thread.
// 2-register load pipeline (no spill), 1 barrier per chunk.
__global__ void __launch_bounds__(1024)
k5_scan(const u64* __restrict__ maskT,
        const float* __restrict__ topv,
        const float4* __restrict__ boxesws,
        float* __restrict__ out)
{
    const int b = blockIdx.x;
    const int t = threadIdx.x;
    const int lane = t & 63;
    const int wv = t >> 6;              // wave id == chunk id

    __shared__ u64 intrarow[64];
    __shared__ u64 keeparr[16];

    const u64* mt = maskT + (size_t)b * 16 * 1024;
    const float* tv = topv + (size_t)b * K_N;

    const bool inr = t < K_N;
    const float myv = tv[inr ? t : 0];
    const bool valid = inr && (myv >= 0.5f);
    bool suppressed = false;

    u64 wcur = inr ? mt[t] : 0ull;      // my row's word 0 (coalesced)

#pragma unroll
    for (int d = 0; d < 16; ++d) {
        u64 wnext = 0ull;
        if (d < 15 && inr) wnext = mt[(size_t)(d + 1) * 1024 + t];  // prefetch
        if (wv == d) {
            intrarow[lane] = wcur;      // same wave writes & reads: no block barrier
            __builtin_amdgcn_wave_barrier();
            u64 validw = __ballot(valid && !suppressed);
            u64 cw = 0ull, keepw = 0ull;
            for (int r = 0; r < 64; ++r) {
                bool kb = ((validw >> r) & 1ull) && !((cw >> r) & 1ull);
                cw |= kb ? intrarow[r] : 0ull;
                keepw |= (kb ? 1ull : 0ull) << r;
            }
            if (lane == 0) keeparr[d] = keepw;
        }
        __syncthreads();
        if (wcur & keeparr[d]) suppressed = true;
        wcur = wnext;
    }

    // outputs: boxes*keep, scores*keep, keep
    float* out_boxes  = out + (size_t)B_N * K_N;          // 32000
    float* out_scores = out + (size_t)6 * B_N * K_N;      // 192000
    float* out_keep   = out + (size_t)7 * B_N * K_N;      // 224000
    if (inr) {
        float kf = ((keeparr[wv] >> lane) & 1ull) ? 1.0f : 0.0f;
        float4 bx = boxesws[(size_t)b * K_N + t];
        size_t o = (size_t)b * K_N + t;
        out_boxes[o * 4 + 0] = bx.x * kf;
        out_boxes[o * 4 + 1] = bx.y * kf;
        out_boxes[o * 4 + 2] = bx.z * kf;
        out_boxes[o * 4 + 3] = bx.w * kf;
        out_scores[o] = myv * kf;
        out_keep[o] = kf;
    }
}

// ---------------------------------------------------------------- launch
extern "C" void kernel_launch(void* const* d_in, const int* in_sizes, int n_in,
                              void* d_out, int out_size, void* d_ws, size_t ws_size,
                              hipStream_t stream)
{
    const float* ptxywh  = (const float*)d_in[0];
    const float* pcls    = (const float*)d_in[1];
    const float* anchors = (const float*)d_in[2];
    float* out = (float*)d_out;

    char* ws = (char*)d_ws;
    size_t o = 0;
    float* pscore = (float*)(ws + o);               o += (size_t)B_N * A_N * 4;
    int*   topi   = (int*)(ws + o);                 o += (size_t)B_N * K_N * 4;
    float* topv   = (float*)(ws + o);               o += (size_t)B_N * K_N * 4;
    float4* boxesws = (float4*)(ws + o);            o += (size_t)B_N * K_N * 16;
    int*   labelsws = (int*)(ws + o);               o += (size_t)B_N * K_N * 4;
    u64* maskT = (u64*)(ws + o);                    o += (size_t)B_N * 16 * 1024 * 8;

    int total = B_N * A_N;
    k1_score<<<(total + 255) / 256, 256, 0, stream>>>(pcls, pscore, total);
    k2_topk<<<B_N, 1024, 0, stream>>>(pscore, topi, topv);
    k3_decode<<<(B_N * K_N + 255) / 256, 256, 0, stream>>>(ptxywh, pcls, anchors,
                                                           topi, boxesws, labelsws, out);
    k4_mask<<<dim3(16, B_N), 256, 0, stream>>>(boxesws, labelsws, maskT);
    k5_scan<<<B_N, 1024, 0, stream>>>(maskT, topv, boxesws, out);
}

// Round 4
// 139.060 us; speedup vs baseline: 1.6061x; 1.6061x over previous
//
#include <hip/hip_runtime.h>
#include <hip/hip_bf16.h>

#pragma clang fp contract(off)

#define B_N 32
#define A_N 32526
#define C_N 20
#define K_N 1000
#define CH_N 8
#define CHSZ 4066   // ceil(A_N / CH_N)

typedef unsigned long long u64;

// ---------------------------------------------------------------- descent
// exact K-th largest u64 key among the block's keys (keys unique, pads = 0).
// key layout: [61:32]=score bits, [31:15]=0x1FFFF (idx<32768), [14:0]=~idx.
// 2-bit MSB descent, one barrier per round (double-buffered wsum).
template<int NE, int NW>
__device__ inline u64 kth_key(const u64* key, u64 (&wsum)[2][NW], unsigned K)
{
    const int tid = threadIdx.x;
    const int lane = tid & 63, wv = tid >> 6;
    int slot = 0;
    auto bs3 = [&](unsigned a, unsigned b, unsigned c) -> u64 {
        u64 s = (u64)a | ((u64)b << 21) | ((u64)c << 42);
#pragma unroll
        for (int off = 32; off > 0; off >>= 1) s += __shfl_down(s, off);
        if (lane == 0) wsum[slot][wv] = s;
        __syncthreads();
        u64 t = 0;
#pragma unroll
        for (int w = 0; w < NW; ++w) t += wsum[slot][w];
        slot ^= 1;
        return t;
    };
    u64 V = 0;
    // score bits 61..32
#pragma unroll 1
    for (int sh = 60; sh >= 32; sh -= 2) {
        u64 X1 = V | (1ull << sh), X2 = V | (2ull << sh), X3 = V | (3ull << sh);
        unsigned c1 = 0, c2 = 0, c3 = 0;
#pragma unroll
        for (int i = 0; i < NE; ++i) {
            c1 += (key[i] >= X1); c2 += (key[i] >= X2); c3 += (key[i] >= X3);
        }
        u64 s = bs3(c1, c2, c3);
        unsigned s1 = (unsigned)(s & 0x1FFFFFu);
        unsigned s2 = (unsigned)((s >> 21) & 0x1FFFFFu);
        unsigned s3 = (unsigned)(s >> 42);
        if (s3 >= K) V = X3; else if (s2 >= K) V = X2; else if (s1 >= K) V = X1;
    }
    V |= 0xFFFF8000ull;   // constant idx-field high bits (idx < 32768)
    // idx bits 14..1
#pragma unroll 1
    for (int sh = 13; sh >= 1; sh -= 2) {
        u64 X1 = V | (1ull << sh), X2 = V | (2ull << sh), X3 = V | (3ull << sh);
        unsigned c1 = 0, c2 = 0, c3 = 0;
#pragma unroll
        for (int i = 0; i < NE; ++i) {
            c1 += (key[i] >= X1); c2 += (key[i] >= X2); c3 += (key[i] >= X3);
        }
        u64 s = bs3(c1, c2, c3);
        unsigned s1 = (unsigned)(s & 0x1FFFFFu);
        unsigned s2 = (unsigned)((s >> 21) & 0x1FFFFFu);
        unsigned s3 = (unsigned)(s >> 42);
        if (s3 >= K) V = X3; else if (s2 >= K) V = X2; else if (s1 >= K) V = X1;
    }
    {   // bit 0
        u64 X = V | 1ull;
        unsigned c = 0;
#pragma unroll
        for (int i = 0; i < NE; ++i) c += (key[i] >= X);
        if ((unsigned)(bs3(c, 0, 0) & 0x1FFFFFu) >= K) V = X;
    }
    return V;
}

// ---------------------------------------------------------------- kernel 2a
// fused: sigmoid(max logits) -> u64 key -> exact local top-1000 per chunk
__global__ void __launch_bounds__(512)
k2a_select(const float* __restrict__ pcls, u64* __restrict__ cand)
{
    const int chunk = blockIdx.x, b = blockIdx.y;
    const int tid = threadIdx.x, lane = tid & 63;
    __shared__ u64 wsum[2][8];
    __shared__ unsigned cnt_s;
    if (tid == 0) cnt_s = 0;

    u64 key[8];
#pragma unroll
    for (int i = 0; i < 8; ++i) {
        int al = tid + i * 512;
        int a = chunk * CHSZ + al;
        u64 k = 0;
        if (al < CHSZ && a < A_N) {
            const float4* p = (const float4*)(pcls + ((size_t)b * A_N + a) * C_N);
            float m = -INFINITY;
#pragma unroll
            for (int q = 0; q < 5; ++q) {
                float4 v = p[q];
                m = fmaxf(m, fmaxf(fmaxf(v.x, v.y), fmaxf(v.z, v.w)));
            }
            double e = exp(-(double)m);                 // exact sigmoid path
            float s = (float)(1.0 / (1.0 + e));
            k = ((u64)__float_as_uint(s) << 32) | (u64)(0xFFFFFFFFu - (unsigned)a);
        }
        key[i] = k;
    }

    u64 V = kth_key<8, 8>(key, wsum, K_N);   // barriers inside cover cnt_s init

    u64* cb = cand + ((size_t)b * CH_N + chunk) * K_N;
#pragma unroll
    for (int i = 0; i < 8; ++i) {
        bool win = key[i] >= V;              // exactly K_N winners (keys unique)
        u64 wm = __ballot(win);
        unsigned base = 0;
        if (lane == 0 && wm) base = atomicAdd(&cnt_s, (unsigned)__popcll(wm));
        base = __shfl(base, 0);
        if (win)
            cb[base + (unsigned)__popcll(wm & ((1ull << lane) - 1ull))] = key[i];
    }
}

// ---------------------------------------------------------------- kernel 2b
// merge 8 x 1000 candidates -> exact global top-1000 set (unsorted)
__global__ void __launch_bounds__(512)
k2b_merge(const u64* __restrict__ cand, u64* __restrict__ winuns)
{
    const int b = blockIdx.x;
    const int tid = threadIdx.x, lane = tid & 63;
    __shared__ u64 wsum[2][8];
    __shared__ unsigned cnt_s;
    if (tid == 0) cnt_s = 0;

    u64 key[16];
    const u64* cb = cand + (size_t)b * (CH_N * K_N);
#pragma unroll
    for (int i = 0; i < 16; ++i) {
        int idx = tid + i * 512;
        key[i] = (idx < CH_N * K_N) ? cb[idx] : 0ull;
    }

    u64 V = kth_key<16, 8>(key, wsum, K_N);

    u64* wb = winuns + (size_t)b * K_N;
#pragma unroll
    for (int i = 0; i < 16; ++i) {
        bool win = key[i] >= V;
        u64 wm = __ballot(win);
        unsigned base = 0;
        if (lane == 0 && wm) base = atomicAdd(&cnt_s, (unsigned)__popcll(wm));
        base = __shfl(base, 0);
        if (win)
            wb[base + (unsigned)__popcll(wm & ((1ull << lane) - 1ull))] = key[i];
    }
}

// ---------------------------------------------------------------- kernel 2c
// rank each winner among the 1000 (keys unique -> bijective) and scatter
// sorted topi/topv. 8 blocks per batch, 8 threads per winner.
__global__ void __launch_bounds__(1024)
k2c_rank(const u64* __restrict__ winuns,
         int* __restrict__ topi, float* __restrict__ topv)
{
    const int bc = blockIdx.x;   // 0..7
    const int b = blockIdx.y;
    const int tid = threadIdx.x;
    __shared__ u64 skey[K_N];
    if (tid < K_N) skey[tid] = winuns[(size_t)b * K_N + tid];
    __syncthreads();

    const int wl = tid >> 3, seg = tid & 7;
    const bool act = wl < 125;
    const int w = bc * 125 + (act ? wl : 0);
    u64 myk = skey[w];
    unsigned cnt = 0;
    const int j0 = seg * 125;
#pragma unroll 5
    for (int j = 0; j < 125; ++j) cnt += (skey[j0 + j] > myk);
    cnt += __shfl_xor(cnt, 1);
    cnt += __shfl_xor(cnt, 2);
    cnt += __shfl_xor(cnt, 4);
    if (act && seg == 0) {
        topi[(size_t)b * K_N + cnt] = (int)(0xFFFFFFFFu - (unsigned)(myk & 0xFFFFFFFFull));
        topv[(size_t)b * K_N + cnt] = __uint_as_float((unsigned)(myk >> 32));
    }
}

// ---------------------------------------------------------------- kernel 3
__global__ void k3_decode(const float* __restrict__ ptxywh,
                          const float* __restrict__ pcls,
                          const float* __restrict__ anchors,
                          const int* __restrict__ topi,
                          float4* __restrict__ boxesws,
                          int* __restrict__ labelsws,
                          float* __restrict__ out)
{
    int t = blockIdx.x * blockDim.x + threadIdx.x;
    if (t >= B_N * K_N) return;
    int b = t / K_N;
    int a = topi[t];

    float4 tb = ((const float4*)ptxywh)[(size_t)b * A_N + a];
    float4 an = ((const float4*)anchors)[a];

    float xx = an.x + (tb.x * 0.1f) * an.z;
    float yy = an.y + (tb.y * 0.1f) * an.w;
    float ww = an.z * (float)exp((double)(tb.z * 0.2f));
    float hh = an.w * (float)exp((double)(tb.w * 0.2f));
    float hw = ww * 0.5f, hh2 = hh * 0.5f;
    boxesws[t] = make_float4(xx - hw, yy - hh2, xx + hw, yy + hh2);

    const float4* pc = (const float4*)(pcls + ((size_t)b * A_N + a) * C_N);
    float m = -INFINITY; int lab = 0;
#pragma unroll
    for (int q = 0; q < 5; ++q) {
        float4 v = pc[q];
        if (v.x > m) { m = v.x; lab = q * 4 + 0; }
        if (v.y > m) { m = v.y; lab = q * 4 + 1; }
        if (v.z > m) { m = v.z; lab = q * 4 + 2; }
        if (v.w > m) { m = v.w; lab = q * 4 + 3; }
    }
    labelsws[t] = lab + 1;

    out[t] = (float)b;                                 // ids_batch
    out[5 * B_N * K_N + t] = (float)(lab + 1);         // labels
}

// ---------------------------------------------------------------- kernel 4
// suppression bitmask, TRANSPOSED layout: maskT[(b*16 + w)*1024 + i]
__global__ void k4_mask(const float4* __restrict__ boxesws,
                        const int* __restrict__ labelsws,
                        u64* __restrict__ maskT)
{
    const int b = blockIdx.y;
    const int tid = threadIdx.x;
    __shared__ float4 obox[K_N];
    __shared__ float oarea[K_N];

    for (int idx = tid; idx < K_N; idx += 256) {
        float4 bx = boxesws[(size_t)b * K_N + idx];
        float off = (float)labelsws[(size_t)b * K_N + idx] * 10.0f;
        float l = bx.x + off, t2 = bx.y + off, r = bx.z + off, bo = bx.w + off;
        obox[idx] = make_float4(l, t2, r, bo);
        oarea[idx] = (r - l) * (bo - t2);
    }
    __syncthreads();

    const int il = tid & 63;
    const int i = blockIdx.x * 64 + il;
    if (i >= K_N) return;
    float4 bi = obox[i];
    float ai = oarea[i];
#pragma unroll
    for (int p = 0; p < 4; ++p) {
        int w = (tid >> 6) + p * 4;
        u64 word = 0ull;
        for (int jj = 0; jj < 64; ++jj) {
            int j = w * 64 + jj;
            if (j < K_N && j != i) {
                float4 bj = obox[j];
                float lx = fmaxf(bi.x, bj.x);
                float ly = fmaxf(bi.y, bj.y);
                float rx = fminf(bi.z, bj.z);
                float ry = fminf(bi.w, bj.w);
                float wx = fmaxf(rx - lx, 0.0f);
                float wy = fmaxf(ry - ly, 0.0f);
                float inter = wx * wy;
                float uni = ai + oarea[j] - inter;
                float den = fmaxf(uni, 1e-9f);
                float iou = inter / den;
                if (iou > 0.5f) word |= (1ull << jj);
            }
        }
        maskT[((size_t)b * 16 + w) * 1024 + i] = word;
    }
}

// ---------------------------------------------------------------- kernel 5
// greedy NMS scan. Diagonal 64x64 block scanned in SCALAR registers:
// rows prefetched via readlane (pipelined), then a pure-SALU
// bitcmp/cselect/andn2 chain. Final pend == keep set (kept rows never
// mutually suppress; diag bits are 0).
__global__ void __launch_bounds__(1024)
k5_scan(const u64* __restrict__ maskT,
        const float* __restrict__ topv,
        const float4* __restrict__ boxesws,
        float* __restrict__ out)
{
    const int b = blockIdx.x;
    const int t = threadIdx.x;
    const int lane = t & 63;
    const int wv = t >> 6;              // wave id == chunk id

    __shared__ u64 keeparr[16];

    const u64* mt = maskT + (size_t)b * 16 * 1024;
    const float* tv = topv + (size_t)b * K_N;

    const bool inr = t < K_N;
    const float myv = tv[inr ? t : 0];
    const bool valid = inr && (myv >= 0.5f);
    bool suppressed = false;

    u64 wcur = inr ? mt[t] : 0ull;      // my row's word 0 (coalesced)

#pragma unroll 1
    for (int d = 0; d < 16; ++d) {
        u64 wnext = 0ull;
        if (d < 15 && inr) wnext = mt[(size_t)(d + 1) * 1024 + t];  // prefetch
        if (wv == d) {
            unsigned wlo = (unsigned)wcur, whi = (unsigned)(wcur >> 32);
            u64 pend = __ballot(valid && !suppressed);
#pragma unroll
            for (int r = 0; r < 64; ++r) {
                u64 roww = ((u64)(unsigned)__builtin_amdgcn_readlane(whi, r) << 32)
                         |  (u64)(unsigned)__builtin_amdgcn_readlane(wlo, r);
                u64 take = ((pend >> r) & 1ull) ? roww : 0ull;
                pend &= ~take;
            }
            if (lane == 0) keeparr[d] = pend;   // pend == keep set for chunk d
        }
        __syncthreads();
        if (wcur & keeparr[d]) suppressed = true;
        wcur = wnext;
    }

    // outputs: boxes*keep, scores*keep, keep
    float* out_boxes  = out + (size_t)B_N * K_N;          // 32000
    float* out_scores = out + (size_t)6 * B_N * K_N;      // 192000
    float* out_keep   = out + (size_t)7 * B_N * K_N;      // 224000
    if (inr) {
        float kf = ((keeparr[wv] >> lane) & 1ull) ? 1.0f : 0.0f;
        float4 bx = boxesws[(size_t)b * K_N + t];
        size_t o = (size_t)b * K_N + t;
        out_boxes[o * 4 + 0] = bx.x * kf;
        out_boxes[o * 4 + 1] = bx.y * kf;
        out_boxes[o * 4 + 2] = bx.z * kf;
        out_boxes[o * 4 + 3] = bx.w * kf;
        out_scores[o] = myv * kf;
        out_keep[o] = kf;
    }
}

// ---------------------------------------------------------------- launch
extern "C" void kernel_launch(void* const* d_in, const int* in_sizes, int n_in,
                              void* d_out, int out_size, void* d_ws, size_t ws_size,
                              hipStream_t stream)
{
    const float* ptxywh  = (const float*)d_in[0];
    const float* pcls    = (const float*)d_in[1];
    const float* anchors = (const float*)d_in[2];
    float* out = (float*)d_out;

    char* ws = (char*)d_ws;
    size_t o = 0;
    u64* cand   = (u64*)(ws + o);   o += (size_t)B_N * CH_N * K_N * 8;  // 2,048,000
    u64* winuns = (u64*)(ws + o);   o += (size_t)B_N * K_N * 8;         //   256,000
    int*   topi = (int*)(ws + o);   o += (size_t)B_N * K_N * 4;
    float* topv = (float*)(ws + o); o += (size_t)B_N * K_N * 4;
    float4* boxesws = (float4*)(ws + o); o += (size_t)B_N * K_N * 16;
    int* labelsws   = (int*)(ws + o);    o += (size_t)B_N * K_N * 4;
    u64* maskT = (u64*)(ws + o);    o += (size_t)B_N * 16 * 1024 * 8;   // 4,194,304
    // total ~7.4 MB

    k2a_select<<<dim3(CH_N, B_N), 512, 0, stream>>>(pcls, cand);
    k2b_merge<<<B_N, 512, 0, stream>>>(cand, winuns);
    k2c_rank<<<dim3(8, B_N), 1024, 0, stream>>>(winuns, topi, topv);
    k3_decode<<<(B_N * K_N + 255) / 256, 256, 0, stream>>>(ptxywh, pcls, anchors,
                                                           topi, boxesws, labelsws, out);
    k4_mask<<<dim3(16, B_N), 256, 0, stream>>>(boxesws, labelsws, maskT);
    k5_scan<<<B_N, 1024, 0, stream>>>(maskT, topv, boxesws, out);
}